// Round 3
// baseline (552.822 us; speedup 1.0000x reference)
//
#include <hip/hip_runtime.h>
#include <stdint.h>

constexpr int N_VOX = 200000;
constexpr int CIN   = 128;
constexpr int DM    = 128;
constexpr int NXC   = 400;
constexpr int NXY   = 160000;   // 400*400
constexpr int NPIX  = 640000;   // 4*160000
constexpr int PIXB  = 256;      // pixels per block (160000 % 256 == 0 -> one batch image per block)
constexpr int NBLK  = NPIX / PIXB;   // 2500

typedef __attribute__((ext_vector_type(8))) short short8v;
typedef __attribute__((ext_vector_type(4))) float f32x4;
typedef __attribute__((ext_vector_type(4))) uint32_t u32x4;

__device__ __forceinline__ uint32_t pack_bf16_pair(float lo, float hi) {
  // RNE float->bf16, pack two into one u32 (lo = even element, hi = odd element)
  uint32_t ul = __float_as_uint(lo);
  uint32_t uh = __float_as_uint(hi);
  ul += 0x7fffu + ((ul >> 16) & 1u);
  uh += 0x7fffu + ((uh >> 16) & 1u);
  return (ul >> 16) | (uh & 0xffff0000u);
}

// ---- prep: W0 f32 [c][k] -> packed bf16-pair words, LINEAR layout (no swizzle) ----
// word i = c*64 + w holds bf16(W0[c][2w]), bf16(W0[c][2w+1])
__global__ void w0conv_k(const float* __restrict__ W0, uint32_t* __restrict__ w0b) {
  int i = blockIdx.x * 256 + threadIdx.x;          // 8192 words total
  int c = i >> 6;
  int w = i & 63;
  float2 f = *(const float2*)(W0 + c * CIN + w * 2);
  w0b[i] = pack_bf16_pair(f.x, f.y);
}

__global__ void init_inv_k(int4* __restrict__ inv4) {
  int i = blockIdx.x * 256 + threadIdx.x;          // NPIX/4 = 160000 = 625*256
  inv4[i] = make_int4(-1, -1, -1, -1);
}

__global__ void scatter_inv_k(const int4* __restrict__ coors, int* __restrict__ inv) {
  int v = blockIdx.x * 256 + threadIdx.x;
  if (v < N_VOX) {
    int4 c = coors[v];                             // {b, z, y, x}
    inv[c.x * NXY + c.z * NXC + c.w] = v;
  }
}

// Dense-M fused GEMM+scatter: one block = 256 contiguous pixels, 4 waves.
// Wave w owns channels [w*32, w*32+32) (2 MFMA ct-tiles) with W0 fragments in
// REGISTERS (32 VGPR). No LDS, no barriers. Empty pixel slots feed zero rows
// to the MFMA; stores are per-element masked to 0.0 via an int4 inv read.
__launch_bounds__(256, 4)
__global__ void fused_k(const float* __restrict__ xin,
                        const uint32_t* __restrict__ w0b,
                        const float* __restrict__ b0,
                        const int* __restrict__ inv,
                        float* __restrict__ out) {
  const int tid  = threadIdx.x;
  const int lane = tid & 63;
  const int wv   = tid >> 6;
  const int c16  = lane & 15;       // column within a 16-wide tile
  const int p    = lane >> 4;       // lane quarter: k-slice for A/B, pixel-quad for C

  // ---- B fragments from global (L2-hot after first block): 2 ct x 4 s ----
  // lane holds W0[c = ct*16+c16][k = s*32 + p*8 + i], i=0..7
  short8v bfr[2][4];
  float bias[2];
  #pragma unroll
  for (int ci = 0; ci < 2; ++ci) {
    const int c = (wv * 2 + ci) * 16 + c16;
    #pragma unroll
    for (int s = 0; s < 4; ++s)
      bfr[ci][s] = *(const short8v*)(w0b + c * 64 + s * 16 + p * 4);
    bias[ci] = b0[c];
  }

  const int pixbase = blockIdx.x * PIXB;
  const int bb      = pixbase / NXY;
  const int yx0     = pixbase - bb * NXY;
  float* const outb = out + (size_t)bb * DM * NXY + yx0;  // + ch*NXY + local px

  for (int mt = 0; mt < PIXB / 16; ++mt) {
    const int lpx = mt * 16;

    // ---- A fragment: row = c16 (pixel slot), k = s*32 + p*8 + i ----
    const int vrow = inv[pixbase + lpx + c16];
    float4 xa[4], xb[4];
    #pragma unroll
    for (int s = 0; s < 4; ++s) {
      xa[s] = make_float4(0.f, 0.f, 0.f, 0.f);
      xb[s] = make_float4(0.f, 0.f, 0.f, 0.f);
    }
    if (vrow >= 0) {
      const float* xr = xin + (size_t)vrow * CIN + p * 8;
      #pragma unroll
      for (int s = 0; s < 4; ++s) {
        xa[s] = *(const float4*)(xr + s * 32);
        xb[s] = *(const float4*)(xr + s * 32 + 4);
      }
    }
    short8v afr[4];
    #pragma unroll
    for (int s = 0; s < 4; ++s) {
      union { short8v sv; u32x4 uv; } cv;
      cv.uv.x = pack_bf16_pair(xa[s].x, xa[s].y);   // pack(0,0) == 0 -> empty rows are zero
      cv.uv.y = pack_bf16_pair(xa[s].z, xa[s].w);
      cv.uv.z = pack_bf16_pair(xb[s].x, xb[s].y);
      cv.uv.w = pack_bf16_pair(xb[s].z, xb[s].w);
      afr[s] = cv.sv;
    }

    // ---- MFMA: 2 ct-tiles x 4 k-steps ----
    f32x4 acc[2];
    {
      f32x4 z = {0.f, 0.f, 0.f, 0.f};
      acc[0] = z; acc[1] = z;
    }
    #pragma unroll
    for (int s = 0; s < 4; ++s) {
      acc[0] = __builtin_amdgcn_mfma_f32_16x16x32_bf16(afr[s], bfr[0][s], acc[0], 0, 0, 0);
      acc[1] = __builtin_amdgcn_mfma_f32_16x16x32_bf16(afr[s], bfr[1][s], acc[1], 0, 0, 0);
    }

    // ---- store: C/D col = c16 (channel), row = p*4+e (pixel); float4 per ct ----
    const int4 vq = *(const int4*)(inv + pixbase + lpx + p * 4);
    #pragma unroll
    for (int ci = 0; ci < 2; ++ci) {
      const int ch = (wv * 2 + ci) * 16 + c16;
      f32x4 v;
      v[0] = (vq.x >= 0) ? acc[ci][0] + bias[ci] : 0.0f;
      v[1] = (vq.y >= 0) ? acc[ci][1] + bias[ci] : 0.0f;
      v[2] = (vq.z >= 0) ? acc[ci][2] + bias[ci] : 0.0f;
      v[3] = (vq.w >= 0) ? acc[ci][3] + bias[ci] : 0.0f;
      *(f32x4*)(outb + (size_t)ch * NXY + lpx + p * 4) = v;
    }
  }
}

extern "C" void kernel_launch(void* const* d_in, const int* in_sizes, int n_in,
                              void* d_out, int out_size, void* d_ws, size_t ws_size,
                              hipStream_t stream) {
  (void)in_sizes; (void)n_in; (void)out_size; (void)ws_size;
  const float* xin  = (const float*)d_in[0];
  const float* W0   = (const float*)d_in[1];
  const float* b0   = (const float*)d_in[2];
  const int*  coors = (const int*)d_in[3];
  float* out = (float*)d_out;

  int*      inv = (int*)d_ws;                                    // 2.56 MB
  uint32_t* w0b = (uint32_t*)((char*)d_ws + (size_t)NPIX * 4);   // 32 KB, 16B-aligned

  w0conv_k<<<dim3(32), dim3(256), 0, stream>>>(W0, w0b);
  init_inv_k<<<dim3(NPIX / 4 / 256), dim3(256), 0, stream>>>((int4*)d_ws);
  scatter_inv_k<<<dim3((N_VOX + 255) / 256), dim3(256), 0, stream>>>((const int4*)coors, (int*)d_ws);
  fused_k<<<dim3(NBLK), dim3(256), 0, stream>>>(xin, w0b, b0, (const int*)d_ws, out);
}

// Round 4
// 453.340 us; speedup vs baseline: 1.2194x; 1.2194x over previous
//
#include <hip/hip_runtime.h>
#include <stdint.h>

constexpr int N_VOX = 200000;
constexpr int CIN   = 128;
constexpr int DM    = 128;
constexpr int NXC   = 400;
constexpr int NXY   = 160000;   // 400*400
constexpr int NPIX  = 640000;   // 4*160000
constexpr int TILE  = 128;      // pixels per block (160000 % 128 == 0 -> tile never straddles batch)
constexpr int NBLK  = NPIX / TILE;   // 5000

typedef __attribute__((ext_vector_type(8))) short short8v;
typedef __attribute__((ext_vector_type(4))) float f32x4;
typedef __attribute__((ext_vector_type(4))) uint32_t u32x4;

__device__ __forceinline__ uint32_t pack_bf16_pair(float lo, float hi) {
  // RNE float->bf16, pack two into one u32 (lo = even element, hi = odd element)
  uint32_t ul = __float_as_uint(lo);
  uint32_t uh = __float_as_uint(hi);
  ul += 0x7fffu + ((ul >> 16) & 1u);
  uh += 0x7fffu + ((uh >> 16) & 1u);
  return (ul >> 16) | (uh & 0xffff0000u);
}

// ---- prep: W0 f32 [c][k] -> packed bf16-pair words, LINEAR layout ----
// word i = c*64 + w holds bf16(W0[c][2w]), bf16(W0[c][2w+1])
__global__ void w0conv_k(const float* __restrict__ W0, uint32_t* __restrict__ w0b) {
  int i = blockIdx.x * 256 + threadIdx.x;          // 8192 words total
  int c = i >> 6;
  int w = i & 63;
  float2 f = *(const float2*)(W0 + c * CIN + w * 2);
  w0b[i] = pack_bf16_pair(f.x, f.y);
}

__global__ void init_inv_k(int4* __restrict__ inv4) {
  int i = blockIdx.x * 256 + threadIdx.x;          // NPIX/4 = 160000 = 625*256
  inv4[i] = make_int4(-1, -1, -1, -1);
}

__global__ void scatter_inv_k(const int4* __restrict__ coors, int* __restrict__ inv) {
  int v = blockIdx.x * 256 + threadIdx.x;
  if (v < N_VOX) {
    int4 c = coors[v];                             // {b, z, y, x}
    inv[c.x * NXY + c.z * NXC + c.w] = v;
  }
}

// Fused GEMM+scatter, M-split gather / N-split compute, A exchanged via LDS.
// Block = 128 px = 8 mtiles of 16. Wave wv gathers mtiles {wv, wv+4} (once),
// packs bf16, writes swizzled LDS; one barrier; every wave computes channels
// [wv*32, wv*32+32) (B-fragments in registers) over all 8 mtiles and stores
// masked float4 directly (C/D row = 4 consecutive pixels, col = channel).
// LDS word address: mt*1024 + row*64 + ((kg ^ (row&7)) << 2), kg = 16B group
// of 8 bf16 along k. The XOR balances both the (row x q) write phase and the
// (row x p) read phase to the 8-words/bank b128 minimum (conflict-free).
__launch_bounds__(256, 4)
__global__ void fused_k(const float* __restrict__ xin,
                        const uint32_t* __restrict__ w0b,
                        const float* __restrict__ b0,
                        const int* __restrict__ inv,
                        float* __restrict__ out) {
  __shared__ __align__(16) uint32_t alds[8 * 1024];   // 32 KB: [mt][row][kg^swz]

  const int tid  = threadIdx.x;
  const int lane = tid & 63;
  const int wv   = tid >> 6;
  const int c16  = lane & 15;       // compute phase: channel-in-tile / A row
  const int p    = lane >> 4;       // lane quarter: k-slice for A/B, pixel-quad for C

  // ---- B fragments from global (L2-hot): wave owns ct tiles 2wv, 2wv+1 ----
  // lane holds W0[c = ct*16+c16][k = s*32 + p*8 + i], i=0..7
  short8v bfr[2][4];
  float bias[2];
  #pragma unroll
  for (int ci = 0; ci < 2; ++ci) {
    const int c = (wv * 2 + ci) * 16 + c16;
    #pragma unroll
    for (int s = 0; s < 4; ++s)
      bfr[ci][s] = *(const short8v*)(w0b + c * 64 + s * 16 + p * 4);
    bias[ci] = b0[c];
  }

  const int pix0 = blockIdx.x * TILE;
  const int bb   = pix0 / NXY;
  const int yx0  = pix0 - bb * NXY;
  float* const outb = out + (size_t)bb * DM * NXY + yx0;

  // ---- gather phase: wave wv loads mtiles wv and wv+4, once per block ----
  {
    const int j = lane >> 2;        // row in mtile 0..15
    const int q = lane & 3;         // k-quarter (32 floats = 4 kg groups)
    #pragma unroll
    for (int m = 0; m < 2; ++m) {
      const int mt  = wv + m * 4;
      const int vox = inv[pix0 + mt * 16 + j];
      uint32_t* dst = alds + mt * 1024 + j * 64;
      if (vox >= 0) {
        const float* xr = xin + (size_t)vox * CIN + q * 32;
        #pragma unroll
        for (int t = 0; t < 4; ++t) {
          float4 a = *(const float4*)(xr + t * 8);
          float4 b = *(const float4*)(xr + t * 8 + 4);
          u32x4 wd;
          wd.x = pack_bf16_pair(a.x, a.y);
          wd.y = pack_bf16_pair(a.z, a.w);
          wd.z = pack_bf16_pair(b.x, b.y);
          wd.w = pack_bf16_pair(b.z, b.w);
          const int kg = q * 4 + t;
          *(u32x4*)(dst + ((kg ^ (j & 7)) << 2)) = wd;
        }
      } else {
        u32x4 z = {0u, 0u, 0u, 0u};
        #pragma unroll
        for (int t = 0; t < 4; ++t) {
          const int kg = q * 4 + t;
          *(u32x4*)(dst + ((kg ^ (j & 7)) << 2)) = z;
        }
      }
    }
  }
  __syncthreads();

  // ---- compute phase: all 8 mtiles, this wave's 32 channels ----
  for (int mt = 0; mt < 8; ++mt) {
    // A fragment: row = c16 (pixel slot), k = s*32 + p*8 + i -> kg = s*4 + p
    const uint32_t* abase = alds + mt * 1024 + c16 * 64;
    short8v afr[4];
    #pragma unroll
    for (int s = 0; s < 4; ++s)
      afr[s] = *(const short8v*)(abase + (((s * 4 + p) ^ (c16 & 7)) << 2));

    f32x4 acc[2];
    {
      f32x4 z = {0.f, 0.f, 0.f, 0.f};
      acc[0] = z; acc[1] = z;
    }
    #pragma unroll
    for (int s = 0; s < 4; ++s) {
      acc[0] = __builtin_amdgcn_mfma_f32_16x16x32_bf16(afr[s], bfr[0][s], acc[0], 0, 0, 0);
      acc[1] = __builtin_amdgcn_mfma_f32_16x16x32_bf16(afr[s], bfr[1][s], acc[1], 0, 0, 0);
    }

    // store: C/D col = c16 (channel), row = p*4+e (pixel); masked float4
    const int lpx = mt * 16 + p * 4;
    const int4 vq = *(const int4*)(inv + pix0 + lpx);
    #pragma unroll
    for (int ci = 0; ci < 2; ++ci) {
      const int ch = (wv * 2 + ci) * 16 + c16;
      f32x4 v;
      v[0] = (vq.x >= 0) ? acc[ci][0] + bias[ci] : 0.0f;
      v[1] = (vq.y >= 0) ? acc[ci][1] + bias[ci] : 0.0f;
      v[2] = (vq.z >= 0) ? acc[ci][2] + bias[ci] : 0.0f;
      v[3] = (vq.w >= 0) ? acc[ci][3] + bias[ci] : 0.0f;
      *(f32x4*)(outb + (size_t)ch * NXY + lpx) = v;
    }
  }
}

extern "C" void kernel_launch(void* const* d_in, const int* in_sizes, int n_in,
                              void* d_out, int out_size, void* d_ws, size_t ws_size,
                              hipStream_t stream) {
  (void)in_sizes; (void)n_in; (void)out_size; (void)ws_size;
  const float* xin  = (const float*)d_in[0];
  const float* W0   = (const float*)d_in[1];
  const float* b0   = (const float*)d_in[2];
  const int*  coors = (const int*)d_in[3];
  float* out = (float*)d_out;

  int*      inv = (int*)d_ws;                                    // 2.56 MB
  uint32_t* w0b = (uint32_t*)((char*)d_ws + (size_t)NPIX * 4);   // 32 KB, 16B-aligned

  w0conv_k<<<dim3(32), dim3(256), 0, stream>>>(W0, w0b);
  init_inv_k<<<dim3(NPIX / 4 / 256), dim3(256), 0, stream>>>((int4*)d_ws);
  scatter_inv_k<<<dim3((N_VOX + 255) / 256), dim3(256), 0, stream>>>((const int4*)coors, (int*)d_ws);
  fused_k<<<dim3(NBLK), dim3(256), 0, stream>>>(xin, w0b, b0, (const int*)d_ws, out);
}